// Round 10
// baseline (475.105 us; speedup 1.0000x reference)
//
#include <hip/hip_runtime.h>
#include <hip/hip_bf16.h>

#define N_NODES 100000

typedef unsigned short ushort_t;
typedef __attribute__((ext_vector_type(8))) short short8;
typedef __attribute__((ext_vector_type(4))) float f32x4;

// ---------------------------------------------------------------------------
// helpers
// ---------------------------------------------------------------------------
static __device__ __forceinline__ ushort_t f2bf(float f) {
    unsigned u = __float_as_uint(f);
    unsigned r = u + 0x7FFFu + ((u >> 16) & 1u);   // round-to-nearest-even
    return (ushort_t)(r >> 16);
}
static __device__ __forceinline__ float bf2f(ushort_t h) {
    return __uint_as_float(((unsigned)h) << 16);
}

// split 8 contiguous fp32 into hi/lo bf16 fragments
static __device__ __forceinline__ void split8(const float* __restrict__ xp,
                                              short8& hi, short8& lo) {
    float4 x0 = *(const float4*)xp;
    float4 x1 = *(const float4*)(xp + 4);
    float xs[8] = {x0.x, x0.y, x0.z, x0.w, x1.x, x1.y, x1.z, x1.w};
    #pragma unroll
    for (int j = 0; j < 8; ++j) {
        ushort_t h = f2bf(xs[j]);
        hi[j] = (short)h;
        lo[j] = (short)f2bf(xs[j] - bf2f(h));
    }
}

// ---------------------------------------------------------------------------
// K1: fused weight-pack (28 blocks) + degree histogram (rest)
// ---------------------------------------------------------------------------
__global__ __launch_bounds__(256) void pack_hist(
        const float* __restrict__ W0, const float* __restrict__ W1,
        const float* __restrict__ W2, const float* __restrict__ W3,
        const float* __restrict__ W4, const float* __restrict__ W5,
        ushort_t* H0, ushort_t* L0, ushort_t* H1, ushort_t* L1,
        ushort_t* H2, ushort_t* L2, ushort_t* H3, ushort_t* L3,
        ushort_t* H4, ushort_t* L4, ushort_t* H5, ushort_t* L5,
        const int* __restrict__ dst, int* __restrict__ deg, int E) {
    int b = blockIdx.x;
    if (b >= 28) {                       // histogram path
        int e = (b - 28) * 256 + threadIdx.x;
        if (e < E) atomicAdd(&deg[__builtin_nontemporal_load(&dst[e])], 1);
        return;
    }
    const float* W; ushort_t* Hi; ushort_t* Lo; int K, NS, base;
    if (b < 8)       { W = W0; Hi = H0; Lo = L0; K = 128; NS = 128; base = 0;  }
    else if (b < 16) { W = W1; Hi = H1; Lo = L1; K = 128; NS = 128; base = 8;  }
    else if (b < 20) { W = W2; Hi = H2; Lo = L2; K = 128; NS = 64;  base = 16; }
    else if (b < 24) { W = W3; Hi = H3; Lo = L3; K = 128; NS = 64;  base = 20; }
    else if (b < 26) { W = W4; Hi = H4; Lo = L4; K = 64;  NS = 64;  base = 24; }
    else             { W = W5; Hi = H5; Lo = L5; K = 64;  NS = 64;  base = 26; }
    int tid = (b - base) * 256 + threadIdx.x;
    if (tid >= (K * NS) / 8) return;
    int l  = tid & 63;
    int fl = tid >> 6;
    int NT = NS / 16;
    int t = fl % NT, s = fl / NT;
    ushort_t hs[8], ls[8];
    #pragma unroll
    for (int j = 0; j < 8; ++j) {
        int k = s * 32 + (l >> 4) * 8 + j;
        int n = t * 16 + (l & 15);
        float w = W[(size_t)k * NS + n];
        ushort_t h = f2bf(w);
        hs[j] = h;
        ls[j] = f2bf(w - bf2f(h));
    }
    #pragma unroll
    for (int j = 0; j < 8; ++j) {
        Hi[(size_t)tid * 8 + j] = hs[j];
        Lo[(size_t)tid * 8 + j] = ls[j];
    }
}

// ---------------------------------------------------------------------------
// scan (3-phase, unchanged from R8)
// ---------------------------------------------------------------------------
__global__ __launch_bounds__(256) void scan_partial_sums(const int* __restrict__ deg,
                                                         int* __restrict__ partials, int N) {
    __shared__ int wsums[4];
    int tid = threadIdx.x, lane = tid & 63, wv = tid >> 6;
    int i0 = blockIdx.x * 1024 + tid * 4;
    int s = 0;
    #pragma unroll
    for (int j = 0; j < 4; ++j) {
        int i = i0 + j;
        if (i < N) s += deg[i];
    }
    #pragma unroll
    for (int off = 32; off > 0; off >>= 1) s += __shfl_xor(s, off, 64);
    if (lane == 0) wsums[wv] = s;
    __syncthreads();
    if (tid == 0)
        partials[blockIdx.x] = wsums[0] + wsums[1] + wsums[2] + wsums[3];
}

__global__ __launch_bounds__(256) void scan_partials(int* __restrict__ partials, int NB,
                                                     int* __restrict__ row_ptr, int N) {
    __shared__ int wsums[4];
    int tid = threadIdx.x, lane = tid & 63, wv = tid >> 6;
    int v = (tid < NB) ? partials[tid] : 0;
    int x = v;
    #pragma unroll
    for (int off = 1; off < 64; off <<= 1) {
        int y = __shfl_up(x, off, 64);
        if (lane >= off) x += y;
    }
    if (lane == 63) wsums[wv] = x;
    __syncthreads();
    int woff = 0;
    for (int w = 0; w < wv; ++w) woff += wsums[w];
    int incl = x + woff;
    if (tid < NB) partials[tid] = incl - v;          // exclusive
    if (tid == NB - 1) row_ptr[N] = incl;            // grand total
}

__global__ __launch_bounds__(256) void scan_emit(const int* __restrict__ deg,
                                                 const int* __restrict__ partials,
                                                 int* __restrict__ row_ptr,
                                                 int* __restrict__ cursor,
                                                 float* __restrict__ inv_deg,
                                                 int* __restrict__ gcur, int N) {
    __shared__ int wsums[4];
    int tid = threadIdx.x, lane = tid & 63, wv = tid >> 6;
    int i0 = blockIdx.x * 1024 + tid * 4;
    int d[4];
    #pragma unroll
    for (int j = 0; j < 4; ++j) {
        int i = i0 + j;
        d[j] = (i < N) ? deg[i] : 0;
    }
    int s = d[0] + d[1] + d[2] + d[3];
    int x = s;
    #pragma unroll
    for (int off = 1; off < 64; off <<= 1) {
        int y = __shfl_up(x, off, 64);
        if (lane >= off) x += y;
    }
    if (lane == 63) wsums[wv] = x;
    __syncthreads();
    int woff = 0;
    for (int w = 0; w < wv; ++w) woff += wsums[w];
    int run = partials[blockIdx.x] + woff + x - s;
    #pragma unroll
    for (int j = 0; j < 4; ++j) {
        int i = i0 + j;
        if (i < N) {
            row_ptr[i] = run;
            cursor[i]  = run;
            inv_deg[i] = 1.0f / (float)(d[j] > 0 ? d[j] : 1);
            if ((i & 255) == 0) gcur[i >> 8] = run;   // bucket staging base
            run += d[j];
        }
    }
}

// ---------------------------------------------------------------------------
// Phase A: bin (src,dst) pairs into bucket-ordered staging (bucket = dst>>8)
// ---------------------------------------------------------------------------
#define MAXBUCK 512
__global__ __launch_bounds__(256) void bin_pairs(const int* __restrict__ src,
                                                 const int* __restrict__ dst,
                                                 int* __restrict__ gcur,
                                                 long long* __restrict__ staged,
                                                 int E, int NBUCK, int C) {
    __shared__ int cnt[MAXBUCK];
    int tid = threadIdx.x;
    int e0 = blockIdx.x * C;
    int e1 = min(e0 + C, E);
    for (int b = tid; b < NBUCK; b += 256) cnt[b] = 0;
    __syncthreads();
    for (int e = e0 + tid; e < e1; e += 256) {
        int d = __builtin_nontemporal_load(&dst[e]);
        atomicAdd(&cnt[d >> 8], 1);
    }
    __syncthreads();
    for (int b = tid; b < NBUCK; b += 256) {
        int c = cnt[b];
        cnt[b] = (c > 0) ? atomicAdd(&gcur[b], c) : 0;
    }
    __syncthreads();
    for (int e = e0 + tid; e < e1; e += 256) {
        int d = __builtin_nontemporal_load(&dst[e]);
        int s = __builtin_nontemporal_load(&src[e]);
        int p = atomicAdd(&cnt[d >> 8], 1);
        staged[p] = ((long long)d << 32) | (unsigned)s;   // hi=dst, lo=src
    }
}

// ---------------------------------------------------------------------------
// K: fused scatter (blocks < NBUCK) + layer-1 fp32 MFMA GEMM (rest).
// Scatter's latency-bound atomics hide under gemm1's compute blocks.
// ---------------------------------------------------------------------------
__global__ __launch_bounds__(256) void scatter_gemm1(
        const long long* __restrict__ staged, const int* __restrict__ row_ptr,
        int* __restrict__ cursor, int* __restrict__ edge_src, int NBUCK, int N,
        const float* __restrict__ X,
        const ushort_t* __restrict__ BsHi, const ushort_t* __restrict__ BsLo,
        const ushort_t* __restrict__ BnHi, const ushort_t* __restrict__ BnLo,
        const float* __restrict__ bias,
        float* __restrict__ S, ushort_t* __restrict__ Zb, int M) {
    constexpr int K = 128, NS = 128;
    constexpr int KS = K / 32, NT = NS / 16;
    __shared__ float ldsS[4][32 * 20];
    __shared__ float ldsZ[4][32 * 20];

    if ((int)blockIdx.x < NBUCK) {       // ---- scatter path ----
        int b = blockIdx.x;
        int lo = b << 8;
        int hiN = min((b + 1) << 8, N);
        int gstart = row_ptr[lo];
        int gend   = row_ptr[hiN];
        for (int p = gstart + threadIdx.x; p < gend; p += 256) {
            long long pr = __builtin_nontemporal_load(&staged[p]);
            int d = (int)(pr >> 32);
            int s = (int)(pr & 0xFFFFFFFFll);
            int pos = atomicAdd(&cursor[d], 1);
            edge_src[pos] = s;
        }
        return;
    }
    // ---- gemm1 path (fp32 X, split hi/lo) ----
    int bid = blockIdx.x - NBUCK;
    int tid = threadIdx.x;
    int lane = tid & 63, w = tid >> 6;
    int baseM = bid * 128 + w * 32;
    int rIn = lane & 15, q = lane >> 4;
    float* bufS = ldsS[w];
    float* bufZ = ldsZ[w];

    short8 Ahi[KS][2], Alo[KS][2];
    #pragma unroll
    for (int s = 0; s < KS; ++s) {
        #pragma unroll
        for (int mt = 0; mt < 2; ++mt) {
            int gm = baseM + mt * 16 + rIn;
            if (gm < M) {
                split8(&X[(size_t)gm * K + s * 32 + q * 8], Ahi[s][mt], Alo[s][mt]);
            } else {
                #pragma unroll
                for (int j = 0; j < 8; ++j) { Ahi[s][mt][j] = 0; Alo[s][mt][j] = 0; }
            }
        }
    }

    for (int t = 0; t < NT; ++t) {
        f32x4 aS0 = {0.f, 0.f, 0.f, 0.f}, aS1 = {0.f, 0.f, 0.f, 0.f};
        f32x4 aZ0 = {0.f, 0.f, 0.f, 0.f}, aZ1 = {0.f, 0.f, 0.f, 0.f};
        #pragma unroll
        for (int s = 0; s < KS; ++s) {
            size_t fo = ((size_t)(s * NT + t) * 64 + lane) * 8;
            short8 bsh = *(const short8*)&BsHi[fo];
            short8 bsl = *(const short8*)&BsLo[fo];
            short8 bnh = *(const short8*)&BnHi[fo];
            short8 bnl = *(const short8*)&BnLo[fo];
            aS0 = __builtin_amdgcn_mfma_f32_16x16x32_bf16(Ahi[s][0], bsh, aS0, 0, 0, 0);
            aS0 = __builtin_amdgcn_mfma_f32_16x16x32_bf16(Alo[s][0], bsh, aS0, 0, 0, 0);
            aS0 = __builtin_amdgcn_mfma_f32_16x16x32_bf16(Ahi[s][0], bsl, aS0, 0, 0, 0);
            aS1 = __builtin_amdgcn_mfma_f32_16x16x32_bf16(Ahi[s][1], bsh, aS1, 0, 0, 0);
            aS1 = __builtin_amdgcn_mfma_f32_16x16x32_bf16(Alo[s][1], bsh, aS1, 0, 0, 0);
            aS1 = __builtin_amdgcn_mfma_f32_16x16x32_bf16(Ahi[s][1], bsl, aS1, 0, 0, 0);
            aZ0 = __builtin_amdgcn_mfma_f32_16x16x32_bf16(Ahi[s][0], bnh, aZ0, 0, 0, 0);
            aZ0 = __builtin_amdgcn_mfma_f32_16x16x32_bf16(Alo[s][0], bnh, aZ0, 0, 0, 0);
            aZ0 = __builtin_amdgcn_mfma_f32_16x16x32_bf16(Ahi[s][0], bnl, aZ0, 0, 0, 0);
            aZ1 = __builtin_amdgcn_mfma_f32_16x16x32_bf16(Ahi[s][1], bnh, aZ1, 0, 0, 0);
            aZ1 = __builtin_amdgcn_mfma_f32_16x16x32_bf16(Alo[s][1], bnh, aZ1, 0, 0, 0);
            aZ1 = __builtin_amdgcn_mfma_f32_16x16x32_bf16(Ahi[s][1], bnl, aZ1, 0, 0, 0);
        }
        #pragma unroll
        for (int r = 0; r < 4; ++r) {
            bufS[(q * 4 + r) * 20 + rIn]      = aS0[r];
            bufS[(16 + q * 4 + r) * 20 + rIn] = aS1[r];
            bufZ[(q * 4 + r) * 20 + rIn]      = aZ0[r];
            bufZ[(16 + q * 4 + r) * 20 + rIn] = aZ1[r];
        }
        int row = lane >> 2;
        int cq  = lane & 3;
        int col = t * 16 + cq * 4;
        float4 bv = *(const float4*)&bias[col];
        #pragma unroll
        for (int half = 0; half < 2; ++half) {
            int gm = baseM + half * 16 + row;
            float4 v = *(float4*)&bufS[(half * 16 + row) * 20 + cq * 4];
            float4 z = *(float4*)&bufZ[(half * 16 + row) * 20 + cq * 4];
            if (gm < M) {
                float4 o;
                o.x = v.x + bv.x; o.y = v.y + bv.y;
                o.z = v.z + bv.z; o.w = v.w + bv.w;
                *(float4*)&S[(size_t)gm * NS + col] = o;
                uint2 o2;
                o2.x = (unsigned)f2bf(z.x) | ((unsigned)f2bf(z.y) << 16);
                o2.y = (unsigned)f2bf(z.z) | ((unsigned)f2bf(z.w) << 16);
                *(uint2*)&Zb[(size_t)gm * NS + col] = o2;
            }
        }
    }
}

// ---------------------------------------------------------------------------
// Layers 2/3: MFMA GEMM with bf16 X (H stored bf16 -> A needs no split;
// only 2 MFMA passes per acc: A*Whi + A*Wlo). Same LDS vector epilogue.
// ---------------------------------------------------------------------------
template <int K, int NS>
__global__ __launch_bounds__(256) void mfma_gemm_bf16(const ushort_t* __restrict__ Xb,
                                                      const ushort_t* __restrict__ BsHi,
                                                      const ushort_t* __restrict__ BsLo,
                                                      const ushort_t* __restrict__ BnHi,
                                                      const ushort_t* __restrict__ BnLo,
                                                      const float* __restrict__ bias,
                                                      float* __restrict__ S,
                                                      ushort_t* __restrict__ Zb,
                                                      int M) {
    constexpr int KS = K / 32, NT = NS / 16;
    __shared__ float ldsS[4][32 * 20];
    __shared__ float ldsZ[4][32 * 20];
    int tid = threadIdx.x;
    int lane = tid & 63, w = tid >> 6;
    int baseM = blockIdx.x * 128 + w * 32;
    int rIn = lane & 15, q = lane >> 4;
    float* bufS = ldsS[w];
    float* bufZ = ldsZ[w];

    short8 A[KS][2];
    #pragma unroll
    for (int s = 0; s < KS; ++s) {
        #pragma unroll
        for (int mt = 0; mt < 2; ++mt) {
            int gm = baseM + mt * 16 + rIn;
            if (gm < M) {
                A[s][mt] = *(const short8*)&Xb[(size_t)gm * K + s * 32 + q * 8];
            } else {
                #pragma unroll
                for (int j = 0; j < 8; ++j) A[s][mt][j] = 0;
            }
        }
    }

    for (int t = 0; t < NT; ++t) {
        f32x4 aS0 = {0.f, 0.f, 0.f, 0.f}, aS1 = {0.f, 0.f, 0.f, 0.f};
        f32x4 aZ0 = {0.f, 0.f, 0.f, 0.f}, aZ1 = {0.f, 0.f, 0.f, 0.f};
        #pragma unroll
        for (int s = 0; s < KS; ++s) {
            size_t fo = ((size_t)(s * NT + t) * 64 + lane) * 8;
            short8 bsh = *(const short8*)&BsHi[fo];
            short8 bsl = *(const short8*)&BsLo[fo];
            short8 bnh = *(const short8*)&BnHi[fo];
            short8 bnl = *(const short8*)&BnLo[fo];
            aS0 = __builtin_amdgcn_mfma_f32_16x16x32_bf16(A[s][0], bsh, aS0, 0, 0, 0);
            aS0 = __builtin_amdgcn_mfma_f32_16x16x32_bf16(A[s][0], bsl, aS0, 0, 0, 0);
            aS1 = __builtin_amdgcn_mfma_f32_16x16x32_bf16(A[s][1], bsh, aS1, 0, 0, 0);
            aS1 = __builtin_amdgcn_mfma_f32_16x16x32_bf16(A[s][1], bsl, aS1, 0, 0, 0);
            aZ0 = __builtin_amdgcn_mfma_f32_16x16x32_bf16(A[s][0], bnh, aZ0, 0, 0, 0);
            aZ0 = __builtin_amdgcn_mfma_f32_16x16x32_bf16(A[s][0], bnl, aZ0, 0, 0, 0);
            aZ1 = __builtin_amdgcn_mfma_f32_16x16x32_bf16(A[s][1], bnh, aZ1, 0, 0, 0);
            aZ1 = __builtin_amdgcn_mfma_f32_16x16x32_bf16(A[s][1], bnl, aZ1, 0, 0, 0);
        }
        #pragma unroll
        for (int r = 0; r < 4; ++r) {
            bufS[(q * 4 + r) * 20 + rIn]      = aS0[r];
            bufS[(16 + q * 4 + r) * 20 + rIn] = aS1[r];
            bufZ[(q * 4 + r) * 20 + rIn]      = aZ0[r];
            bufZ[(16 + q * 4 + r) * 20 + rIn] = aZ1[r];
        }
        int row = lane >> 2;
        int cq  = lane & 3;
        int col = t * 16 + cq * 4;
        float4 bv = *(const float4*)&bias[col];
        #pragma unroll
        for (int half = 0; half < 2; ++half) {
            int gm = baseM + half * 16 + row;
            float4 v = *(float4*)&bufS[(half * 16 + row) * 20 + cq * 4];
            float4 z = *(float4*)&bufZ[(half * 16 + row) * 20 + cq * 4];
            if (gm < M) {
                float4 o;
                o.x = v.x + bv.x; o.y = v.y + bv.y;
                o.z = v.z + bv.z; o.w = v.w + bv.w;
                *(float4*)&S[(size_t)gm * NS + col] = o;
                uint2 o2;
                o2.x = (unsigned)f2bf(z.x) | ((unsigned)f2bf(z.y) << 16);
                o2.y = (unsigned)f2bf(z.z) | ((unsigned)f2bf(z.w) << 16);
                *(uint2*)&Zb[(size_t)gm * NS + col] = o2;
            }
        }
    }
}

// ---------------------------------------------------------------------------
// Aggregate: out[n,f] = act( S[n,f] + inv_deg[n]*sum Z[src,f] )
// uint4 gathers: 8 bf16/lane (halves VMEM instr count vs R9's uint2).
// OUTBF=1 -> bf16 out (relu layers), OUTBF=0 -> fp32 out (softmax).
// ---------------------------------------------------------------------------
template <int D, int ACT, int OUTBF>
__global__ __launch_bounds__(256) void agg_kernel(const float* __restrict__ S,
                                                  const uint4* __restrict__ Zu,
                                                  const int* __restrict__ row_ptr,
                                                  const int* __restrict__ edge_src,
                                                  const float* __restrict__ inv_deg,
                                                  void* __restrict__ outp, int N) {
    constexpr int G  = D / 8;          // lanes per node
    constexpr int NG = 256 / G;        // nodes per block
    int tid = threadIdx.x;
    int g = tid / G, f8 = tid % G;
    int n = blockIdx.x * NG + g;
    if (n >= N) return;
    int beg = row_ptr[n], end = row_ptr[n + 1];

    float a0[8] = {0,0,0,0,0,0,0,0}, a1[8] = {0,0,0,0,0,0,0,0};
    float a2[8] = {0,0,0,0,0,0,0,0}, a3[8] = {0,0,0,0,0,0,0,0};
#define ACC8(u, a)                                                             \
    a[0] += __uint_as_float((u).x << 16);                                      \
    a[1] += __uint_as_float((u).x & 0xFFFF0000u);                              \
    a[2] += __uint_as_float((u).y << 16);                                      \
    a[3] += __uint_as_float((u).y & 0xFFFF0000u);                              \
    a[4] += __uint_as_float((u).z << 16);                                      \
    a[5] += __uint_as_float((u).z & 0xFFFF0000u);                              \
    a[6] += __uint_as_float((u).w << 16);                                      \
    a[7] += __uint_as_float((u).w & 0xFFFF0000u);
    int j = beg;
    for (; j + 3 < end; j += 4) {
        int s0 = __builtin_nontemporal_load(&edge_src[j + 0]);
        int s1 = __builtin_nontemporal_load(&edge_src[j + 1]);
        int s2 = __builtin_nontemporal_load(&edge_src[j + 2]);
        int s3 = __builtin_nontemporal_load(&edge_src[j + 3]);
        uint4 u0 = Zu[(size_t)s0 * G + f8];
        uint4 u1 = Zu[(size_t)s1 * G + f8];
        uint4 u2 = Zu[(size_t)s2 * G + f8];
        uint4 u3 = Zu[(size_t)s3 * G + f8];
        ACC8(u0, a0) ACC8(u1, a1) ACC8(u2, a2) ACC8(u3, a3)
    }
    for (; j < end; ++j) {
        uint4 u = Zu[(size_t)__builtin_nontemporal_load(&edge_src[j]) * G + f8];
        ACC8(u, a0)
    }
#undef ACC8
    float id = inv_deg[n];
    f32x4 s0 = __builtin_nontemporal_load((const f32x4*)(S + (size_t)n * D + f8 * 8));
    f32x4 s1 = __builtin_nontemporal_load((const f32x4*)(S + (size_t)n * D + f8 * 8 + 4));
    float v[8];
    #pragma unroll
    for (int k = 0; k < 8; ++k) {
        float sv = (k < 4) ? s0[k] : s1[k - 4];
        v[k] = sv + id * ((a0[k] + a1[k]) + (a2[k] + a3[k]));
    }

    if (ACT == 0) {
        #pragma unroll
        for (int k = 0; k < 8; ++k) v[k] = fmaxf(v[k], 0.f);
    } else {
        // softmax over D=64 spread across G=8 lanes x 8 vals
        float m = v[0];
        #pragma unroll
        for (int k = 1; k < 8; ++k) m = fmaxf(m, v[k]);
        #pragma unroll
        for (int off = 4; off > 0; off >>= 1) m = fmaxf(m, __shfl_xor(m, off, 8));
        float s = 0.f;
        #pragma unroll
        for (int k = 0; k < 8; ++k) { v[k] = __expf(v[k] - m); s += v[k]; }
        #pragma unroll
        for (int off = 4; off > 0; off >>= 1) s += __shfl_xor(s, off, 8);
        float inv = 1.0f / s;
        #pragma unroll
        for (int k = 0; k < 8; ++k) v[k] *= inv;
    }

    if (OUTBF) {
        uint4 o;
        o.x = (unsigned)f2bf(v[0]) | ((unsigned)f2bf(v[1]) << 16);
        o.y = (unsigned)f2bf(v[2]) | ((unsigned)f2bf(v[3]) << 16);
        o.z = (unsigned)f2bf(v[4]) | ((unsigned)f2bf(v[5]) << 16);
        o.w = (unsigned)f2bf(v[6]) | ((unsigned)f2bf(v[7]) << 16);
        ((uint4*)((ushort_t*)outp + (size_t)n * D))[f8] = o;
    } else {
        float4 o0 = make_float4(v[0], v[1], v[2], v[3]);
        float4 o1 = make_float4(v[4], v[5], v[6], v[7]);
        float* po = (float*)outp + (size_t)n * D + f8 * 8;
        *(float4*)po = o0;
        *(float4*)(po + 4) = o1;
    }
}

// ---------------------------------------------------------------------------
extern "C" void kernel_launch(void* const* d_in, const int* in_sizes, int n_in,
                              void* d_out, int out_size, void* d_ws, size_t ws_size,
                              hipStream_t stream) {
    const float* in_feat = (const float*)d_in[0];
    const int*   src     = (const int*)d_in[1];
    const int*   dst     = (const int*)d_in[2];
    const float* w1s = (const float*)d_in[3];
    const float* w1n = (const float*)d_in[4];
    const float* b1  = (const float*)d_in[5];
    const float* w2s = (const float*)d_in[6];
    const float* w2n = (const float*)d_in[7];
    const float* b2  = (const float*)d_in[8];
    const float* w3s = (const float*)d_in[9];
    const float* w3n = (const float*)d_in[10];
    const float* b3  = (const float*)d_in[11];

    const int N = N_NODES;
    const int E = in_sizes[1];

    char* p = (char*)d_ws;
    auto carve = [&](size_t bytes) -> char* {
        char* q = p;
        p += (bytes + 511) & ~(size_t)511;
        return q;
    };
    float*    S        = (float*)   carve((size_t)N * 128 * sizeof(float));
    ushort_t* Zb       = (ushort_t*)carve((size_t)N * 128 * sizeof(ushort_t));
    ushort_t* Hb       = (ushort_t*)carve((size_t)N * 128 * sizeof(ushort_t));  // bf16 H
    int*      edge_src = (int*)     carve((size_t)E * sizeof(int));
    int*      row_ptr  = (int*)     carve((size_t)(N + 1) * sizeof(int));
    int*      cursor   = (int*)     carve((size_t)N * sizeof(int));
    int*      deg      = (int*)     carve((size_t)N * sizeof(int));
    float*    invd     = (float*)   carve((size_t)N * sizeof(float));
    int*      partials = (int*)     carve(256 * sizeof(int));
    int*      gcur     = (int*)     carve(MAXBUCK * sizeof(int));
    long long* staged  = (long long*)carve((size_t)E * sizeof(long long));
    // packed weights (hi/lo per matrix)
    ushort_t* P1sH = (ushort_t*)carve(128 * 128 * 2); ushort_t* P1sL = (ushort_t*)carve(128 * 128 * 2);
    ushort_t* P1nH = (ushort_t*)carve(128 * 128 * 2); ushort_t* P1nL = (ushort_t*)carve(128 * 128 * 2);
    ushort_t* P2sH = (ushort_t*)carve(128 * 64 * 2);  ushort_t* P2sL = (ushort_t*)carve(128 * 64 * 2);
    ushort_t* P2nH = (ushort_t*)carve(128 * 64 * 2);  ushort_t* P2nL = (ushort_t*)carve(128 * 64 * 2);
    ushort_t* P3sH = (ushort_t*)carve(64 * 64 * 2);   ushort_t* P3sL = (ushort_t*)carve(64 * 64 * 2);
    ushort_t* P3nH = (ushort_t*)carve(64 * 64 * 2);   ushort_t* P3nL = (ushort_t*)carve(64 * 64 * 2);

    const int NBUCK = (N + 255) >> 8;          // 391 buckets of 256 nodes
    const int GB    = (N + 127) / 128;         // 782 gemm row blocks
    const int NB    = (N + 1023) / 1024;       // 98 scan segments

    // ---- K1: pack weights + degree histogram (independent, co-launched) ----
    (void)hipMemsetAsync(deg, 0, (size_t)N * sizeof(int), stream);
    pack_hist<<<28 + (E + 255) / 256, 256, 0, stream>>>(
        w1s, w1n, w2s, w2n, w3s, w3n,
        P1sH, P1sL, P1nH, P1nL, P2sH, P2sL, P2nH, P2nL, P3sH, P3sL, P3nH, P3nL,
        dst, deg, E);

    // ---- scan + bin ----
    scan_partial_sums<<<NB, 256, 0, stream>>>(deg, partials, N);
    scan_partials<<<1, 256, 0, stream>>>(partials, NB, row_ptr, N);
    scan_emit<<<NB, 256, 0, stream>>>(deg, partials, row_ptr, cursor, invd, gcur, N);
    const int BINB  = 256;
    const int CHUNK = (E + BINB - 1) / BINB;
    bin_pairs<<<BINB, 256, 0, stream>>>(src, dst, gcur, staged, E, NBUCK, CHUNK);

    // ---- Layer 1 GEMM co-launched with CSR scatter ----
    scatter_gemm1<<<NBUCK + GB, 256, 0, stream>>>(staged, row_ptr, cursor, edge_src,
                                                  NBUCK, N,
                                                  in_feat, P1sH, P1sL, P1nH, P1nL,
                                                  b1, S, Zb, N);
    agg_kernel<128, 0, 1><<<(N + 15) / 16, 256, 0, stream>>>(
        S, (const uint4*)Zb, row_ptr, edge_src, invd, Hb, N);

    // ---- Layer 2: 128 -> 64, relu ----
    mfma_gemm_bf16<128, 64><<<GB, 256, 0, stream>>>(Hb, P2sH, P2sL, P2nH, P2nL,
                                                    b2, S, Zb, N);
    agg_kernel<64, 0, 1><<<(N + 31) / 32, 256, 0, stream>>>(
        S, (const uint4*)Zb, row_ptr, edge_src, invd, Hb, N);

    // ---- Layer 3: 64 -> 64, softmax ----
    mfma_gemm_bf16<64, 64><<<GB, 256, 0, stream>>>(Hb, P3sH, P3sL, P3nH, P3nL,
                                                   b3, S, Zb, N);
    agg_kernel<64, 1, 0><<<(N + 31) / 32, 256, 0, stream>>>(
        S, (const uint4*)Zb, row_ptr, edge_src, invd, d_out, N);
}